// Round 23
// baseline (987.305 us; speedup 1.0000x reference)
//
#include <hip/hip_runtime.h>
#include <cstdint>

typedef unsigned short u16;
typedef unsigned int   u32;
typedef unsigned long long u64;
using short8 = __attribute__((ext_vector_type(8))) short;
using f32x4  = __attribute__((ext_vector_type(4))) float;

#define S_   2048
#define D_   1024
#define NTOK 4096   /* B*S */

__device__ __forceinline__ u16 f2bf(float f){
  u32 u = __float_as_uint(f);
  u32 r = u + 0x7fffu + ((u >> 16) & 1u);   // RNE
  return (u16)(r >> 16);
}
__device__ __forceinline__ float bf2f(u16 h){
  return __uint_as_float(((u32)h) << 16);
}
__device__ __forceinline__ void gld16(const void* g, void* l){
  __builtin_amdgcn_global_load_lds((__attribute__((address_space(1))) void*)(void*)g,
                                   (__attribute__((address_space(3))) void*)l, 16, 0, 0);
}

// ---------------------------------------------------------------------------
// bf16 MFMA GEMM (NT): C[M,N] = A[M,K] * Bt[N,K]^T, 128x128x32 tiles, 4 waves.
// T2 bank-conflict fix (r15, conflicts = 0).  __launch_bounds__(256,4).
// F_TMFAST: tm-fastest decode (sparse XCD balance, r17: -54us).
// F_GROUP8: 8x8 supertile decode (r20 config).
// ---------------------------------------------------------------------------
enum { F_OUTBF16=1, F_BIAS=2, F_RELU=4, F_RESID=8, F_GATEACC=16,
       F_GATHER=64, F_SCATTER=128, F_EXPB=512, F_SPLITK2=1024, F_BIASHI=2048,
       F_TMFAST=4096, F_BIASKR=8192, F_GROUP8=16384 };

template<int FLAGS>
__global__ void __launch_bounds__(256, 4)
gemm_k(const u16* __restrict__ A, int lda, long sAz,
       const u16* __restrict__ Bt, int ldb, long sBz,
       void* __restrict__ out, int ldo, long sOz,
       float* __restrict__ out2,
       const float* __restrict__ bias,
       const float* __restrict__ resid,
       const float* __restrict__ gv,
       const int* __restrict__ idx,
       const int* __restrict__ slotb,
       const int* __restrict__ cntp, int ebase,
       int K, int ncols)
{
  constexpr int BM = 128, BK = 32;
  const int tid = threadIdx.x;
  const int w = tid >> 6, l = tid & 63;
  const int wr = w >> 1, wc = w & 1;
  const int l4 = l & 15, lh = l >> 4;

  // bijective XCD swizzle
  const int gx = gridDim.x, gy = gridDim.y;
  const int nwg = gx*gy*gridDim.z;
  const int flat = (blockIdx.z*gy + blockIdx.y)*gx + blockIdx.x;
  const int q8 = nwg >> 3, r8 = nwg & 7, xcd = flat & 7, off8 = flat >> 3;
  const int swz = (xcd < r8) ? (xcd*(q8+1) + off8)
                             : (r8*(q8+1) + (xcd-r8)*q8 + off8);
  int tn, tm, z;
  if constexpr (FLAGS & F_TMFAST){
    tm = swz % gy;
    const int rest = swz / gy;
    tn = rest % gx;
    z  = rest / gx;
  } else if constexpr (FLAGS & F_GROUP8){
    const int slice = gx*gy;
    z = swz / slice;
    const int f = swz % slice;
    const int st = f >> 6, within = f & 63;
    const int gx8 = gx >> 3;
    tn = (st % gx8)*8 + (within & 7);
    tm = (st / gx8)*8 + (within >> 3);
  } else {
    tn = swz % gx;
    const int rest = swz / gx;
    tm = rest % gy;
    z  = rest / gy;
  }
  const int ncol0 = tn * 128;

  int kh = 0, ze = z;
  if constexpr (FLAGS & F_SPLITK2){ kh = z & 1; ze = z >> 1; }

  int cnt = 0x7fffffff; long ofs = 0;
  if constexpr (FLAGS & (F_GATHER|F_SCATTER)){
    const int e = ebase + ze;
    cnt = cntp[e]; ofs = (long)cntp[8+e];
    if (tm*BM >= cnt) return;
  }

  const u16 *Abase, *Btbase;
  if constexpr (FLAGS & F_GATHER){
    Abase  = A;                              // rows via idx
    Btbase = Bt + (long)ze*sBz + (long)ncol0*ldb;
  } else if constexpr (FLAGS & F_SCATTER){
    Abase  = A + ofs*lda + (long)tm*BM*lda + (long)kh*K;
    Btbase = Bt + (long)ze*sBz + (long)ncol0*ldb + (long)kh*K;
  } else {
    Abase  = A  + (long)ze*sAz + (long)tm*BM*lda + (long)kh*K;
    Btbase = Bt + (long)ze*sBz + (long)ncol0*ldb + (long)kh*K;
  }

  const int r0 = tid >> 2;
  const int seg = (tid & 3) ^ ((tid >> 3) & 3);   // pre-swizzled source segment
  long aoff0, aoff1;
  if constexpr (FLAGS & F_GATHER){
    const int p0 = tm*BM + r0, p1 = p0 + 64;
    const int t0 = (p0 < cnt) ? idx[ofs + p0] : 0;
    const int t1 = (p1 < cnt) ? idx[ofs + p1] : 0;
    aoff0 = (long)t0*lda; aoff1 = (long)t1*lda;
  } else {
    aoff0 = (long)r0*lda; aoff1 = (long)(r0+64)*lda;
  }
  const u16* pA0 = Abase + aoff0 + seg*8;
  const u16* pA1 = Abase + aoff1 + seg*8;
  const u16* pB0 = Btbase + (long)r0*ldb + seg*8;
  const u16* pB1 = Btbase + (long)(r0+64)*ldb + seg*8;

  __shared__ __align__(16) u16 As[2][BM*BK];
  __shared__ __align__(16) u16 Bs[2][BM*BK];

  f32x4 zero = {0.f,0.f,0.f,0.f};
  f32x4 acc[4][4];
  #pragma unroll
  for (int i=0;i<4;i++)
    #pragma unroll
    for (int j=0;j<4;j++) acc[i][j] = zero;

  const int NK = K >> 5;

  auto stage = [&](int buf, int kt){
    const int k0 = kt*BK;
    gld16(pA0 + k0, &As[buf][(w*64)*8]);
    gld16(pA1 + k0, &As[buf][(256 + w*64)*8]);
    gld16(pB0 + k0, &Bs[buf][(w*64)*8]);
    gld16(pB1 + k0, &Bs[buf][(256 + w*64)*8]);
  };

  stage(0,0);
  __syncthreads();

  const int xr = (l4 >> 1) & 3;                   // read-side involution
  const int lhx = (lh ^ xr) * 8;

  for (int kt=0; kt<NK; ++kt){
    const int cur = kt & 1, nxt = cur ^ 1;
    if (kt+1 < NK) stage(nxt, kt+1);
    short8 a[4], b[4];
    #pragma unroll
    for (int m=0;m<4;m++){
      const int arow = wr*64 + m*16 + l4;
      a[m] = *(const short8*)&As[cur][arow*BK + lhx];
    }
    #pragma unroll
    for (int n=0;n<4;n++){
      const int brow = wc*64 + n*16 + l4;
      b[n] = *(const short8*)&Bs[cur][brow*BK + lhx];
    }
    #pragma unroll
    for (int m=0;m<4;m++)
      #pragma unroll
      for (int n=0;n<4;n++)
        acc[m][n] = __builtin_amdgcn_mfma_f32_16x16x32_bf16(a[m], b[n], acc[m][n], 0, 0, 0);
    __syncthreads();
  }

  // epilogue  (C/D: col = lane&15, row = (lane>>4)*4 + reg)
  float* outf = (float*)out + (long)z*sOz;
  u16*   outh = (u16*)out + (long)z*sOz;
  const float* bp = bias;
  if constexpr (FLAGS & F_EXPB) bp += (long)(ebase+ze)*ncols;
  const long row0 = (long)tm*BM + wr*64;
  #pragma unroll
  for (int m=0;m<4;m++){
    #pragma unroll
    for (int n=0;n<4;n++){
      const int col = ncol0 + wc*64 + n*16 + l4;
      if (col < ncols){
        #pragma unroll
        for (int r=0;r<4;r++){
          const long row = row0 + m*16 + lh*4 + r;
          float v = acc[m][n][r];
          if constexpr (FLAGS & F_BIAS){
            bool addb = true;
            if constexpr (FLAGS & F_SPLITK2) addb = (kh == 0);
            if (addb) v += bp[col];
          }
          if constexpr (FLAGS & F_BIASHI){
            if (col >= 1024) v += bias[col - 1024];
          }
          if constexpr (FLAGS & F_BIASKR){
            if (col >= 1280) v += bias[col - 1280];
          }
          if constexpr (FLAGS & F_RELU) v = fmaxf(v, 0.f);
          if constexpr (FLAGS & F_SCATTER){
            if (row < cnt){
              const long gs = ofs + row;
              const int tok = idx[gs];
              float* dst = (float*)out + (long)(slotb[gs]*2 + kh)*sOz;
              dst[(long)tok*ldo + col] = gv[gs] * v;
            }
          } else if constexpr (FLAGS & F_GATHER){
            if (row < cnt) outh[(ofs + row)*(long)ldo + col] = f2bf(v);
          } else if constexpr (FLAGS & F_GATEACC){
            outf[row*(long)ldo + col] += v;
          } else if constexpr (FLAGS & F_RESID){
            const long off = row*(long)ldo + col;
            outf[off] = resid[off] + v;
          } else if constexpr (FLAGS & F_OUTBF16){
            outh[row*(long)ldo + col] = f2bf(v);
          } else {
            outf[row*(long)ldo + col] = v;
          }
        }
      }
    }
  }
}

// ---------------------------------------------------------------------------
// Flash attention, KV-split x2.  __launch_bounds__(256,2) (r18: (256,3) spills).
// r22: bit-exact defer-rescale guard (sf==1 when tile max doesn't grow).
// ---------------------------------------------------------------------------
#define LDP 136

__global__ void __launch_bounds__(256, 2)
flash_k(const u16* __restrict__ qf, const u16* __restrict__ kf,
        const u16* __restrict__ vt, float* __restrict__ opart,
        float2* __restrict__ ml)
{
  const int bh = blockIdx.x;
  const int qt = blockIdx.y;
  const int kvh = blockIdx.z;
  const int b = bh >> 4, h = bh & 15;
  const int tid = threadIdx.x, w = tid >> 6, l = tid & 63;
  const int l4 = l & 15, lh = l >> 4;

  const u16* Qb = qf + (long)b*4194304 + h*128;
  const u16* Kb = kf + (long)b*4194304 + h*128;
  const u16* Vb = vt + (long)bh*131072;

  short8 qa[2][4];
  #pragma unroll
  for (int m=0;m<2;m++)
    #pragma unroll
    for (int ks=0;ks<4;ks++){
      const long row = qt*128 + w*32 + m*16 + l4;
      qa[m][ks] = *(const short8*)(Qb + row*2048 + ks*32 + lh*8);
    }

  __shared__ __align__(16) u16 KPs[128*LDP];
  __shared__ __align__(16) u16 Vs[64*LDP];

  const float SCL = 0.125f * 1.44269504f;
  float mst[2][4], lst[2][4];
  f32x4 o_acc[2][4];
  #pragma unroll
  for (int m=0;m<2;m++)
    #pragma unroll
    for (int r=0;r<4;r++){ mst[m][r] = -3.0e38f; lst[m][r] = 0.f; }
  #pragma unroll
  for (int m=0;m<2;m++)
    #pragma unroll
    for (int n=0;n<4;n++) o_acc[m][n] = (f32x4){0.f,0.f,0.f,0.f};

  const int t0 = kvh*8;
  for (int t=t0; t<t0+8; t++){
    #pragma unroll
    for (int i=0;i<8;i++){
      const int c = i*256 + tid;
      const int kr = c >> 4, kc = (c & 15) * 8;
      const uint4 v = *(const uint4*)(Kb + (long)(t*128+kr)*2048 + kc);
      *(uint4*)&KPs[kr*LDP + kc] = v;
    }
    #pragma unroll
    for (int i=0;i<4;i++){
      const int c = i*256 + tid;
      const int vr = c >> 4, vc = (c & 15) * 8;
      const uint4 v = *(const uint4*)(Vb + (long)vr*2048 + t*128 + vc);
      *(uint4*)&Vs[vr*LDP + vc] = v;
    }
    __syncthreads();

    f32x4 s[2][8];
    #pragma unroll
    for (int m=0;m<2;m++)
      #pragma unroll
      for (int n=0;n<8;n++) s[m][n] = (f32x4){0.f,0.f,0.f,0.f};
    #pragma unroll
    for (int ks=0;ks<4;ks++){
      short8 bn[8];
      #pragma unroll
      for (int n=0;n<8;n++)
        bn[n] = *(const short8*)&KPs[(n*16+l4)*LDP + ks*32 + lh*8];
      #pragma unroll
      for (int m=0;m<2;m++)
        #pragma unroll
        for (int n=0;n<8;n++)
          s[m][n] = __builtin_amdgcn_mfma_f32_16x16x32_bf16(qa[m][ks], bn[n], s[m][n], 0,0,0);
    }
    __syncthreads();

    #pragma unroll
    for (int m=0;m<2;m++){
      #pragma unroll
      for (int r=0;r<4;r++){
        float pm = s[m][0][r];
        #pragma unroll
        for (int n=1;n<8;n++) pm = fmaxf(pm, s[m][n][r]);
        #pragma unroll
        for (int o=1;o<16;o<<=1) pm = fmaxf(pm, __shfl_xor(pm, o));
        if (pm > mst[m][r]){          // bit-exact: skipped branch has sf==1.0
          const float sf = exp2f((mst[m][r] - pm)*SCL);
          lst[m][r] *= sf;
          #pragma unroll
          for (int n=0;n<4;n++) o_acc[m][n][r] *= sf;
          mst[m][r] = pm;
        }
        float rsum = 0.f;
        #pragma unroll
        for (int n=0;n<8;n++){
          const float p = exp2f((s[m][n][r] - mst[m][r])*SCL);
          s[m][n][r] = p;
          rsum += p;
        }
        #pragma unroll
        for (int o=1;o<16;o<<=1) rsum += __shfl_xor(rsum, o);
        lst[m][r] += rsum;
      }
    }
    #pragma unroll
    for (int m=0;m<2;m++)
      #pragma unroll
      for (int n=0;n<8;n++)
        #pragma unroll
        for (int r=0;r<4;r++)
          KPs[(w*32 + m*16 + lh*4 + r)*LDP + n*16 + l4] = f2bf(s[m][n][r]);
    __syncthreads();

    #pragma unroll
    for (int ks=0;ks<4;ks++){
      short8 pa[2], vb[4];
      #pragma unroll
      for (int m=0;m<2;m++)
        pa[m] = *(const short8*)&KPs[(w*32 + m*16 + l4)*LDP + ks*32 + lh*8];
      #pragma unroll
      for (int n=0;n<4;n++)
        vb[n] = *(const short8*)&Vs[(n*16+l4)*LDP + ks*32 + lh*8];
      #pragma unroll
      for (int m=0;m<2;m++)
        #pragma unroll
        for (int n=0;n<4;n++)
          o_acc[m][n] = __builtin_amdgcn_mfma_f32_16x16x32_bf16(pa[m], vb[n], o_acc[m][n], 0,0,0);
    }
    __syncthreads();
  }

  float* Op = opart + (long)kvh*4194304;
  #pragma unroll
  for (int m=0;m<2;m++){
    #pragma unroll
    for (int r=0;r<4;r++){
      const long srow = qt*128 + w*32 + m*16 + lh*4 + r;
      const long obase = ((long)b*2048 + srow)*1024 + h*64;
      #pragma unroll
      for (int n=0;n<4;n++)
        Op[obase + n*16 + l4] = o_acc[m][n][r];
      if (l4 == 0)
        ml[(long)kvh*65536 + (long)bh*2048 + srow] = make_float2(mst[m][r], lst[m][r]);
    }
  }
}

// merge the two KV-half partials -> bf16 attn rows
__global__ void pvmerge_k(const float* __restrict__ opart,
                          const float2* __restrict__ ml,
                          u16* __restrict__ attn)
{
  const int row = blockIdx.x;          // b*2048 + s
  const int t = threadIdx.x;
  const int b = row >> 11, s = row & 2047;
  const int h = t >> 4;
  const float SCL = 0.125f * 1.44269504f;
  const float2 m0 = ml[(long)(b*16+h)*2048 + s];
  const float2 m1 = ml[65536L + (long)(b*16+h)*2048 + s];
  const float mm = fmaxf(m0.x, m1.x);
  const float s0 = exp2f((m0.x - mm)*SCL);
  const float s1 = exp2f((m1.x - mm)*SCL);
  const float inv = 1.f / (m0.y*s0 + m1.y*s1);
  const float4 a = *(const float4*)&opart[(long)row*1024 + t*4];
  const float4 c = *(const float4*)&opart[4194304L + (long)row*1024 + t*4];
  uint2 pk;
  pk.x = (u32)f2bf((a.x*s0 + c.x*s1)*inv) | ((u32)f2bf((a.y*s0 + c.y*s1)*inv) << 16);
  pk.y = (u32)f2bf((a.z*s0 + c.z*s1)*inv) | ((u32)f2bf((a.w*s0 + c.w*s1)*inv) << 16);
  *(uint2*)&attn[(long)row*1024 + t*4] = pk;
}

// ---------------------------------------------------------------------------
// batched transpose f32 [K][N] (ld=N) -> bf16 [N][K] (ld=K); z via strides.
__global__ void tpose_k(const float* __restrict__ src, u16* __restrict__ dst,
                        int K, int N, long szS, long szD)
{
  __shared__ u16 tile[32][36];
  const int t = threadIdx.x;
  src += (long)blockIdx.z*szS; dst += (long)blockIdx.z*szD;
  const int n0 = blockIdx.x*32, k0 = blockIdx.y*32;
  const int lr = t >> 3, lc = (t & 7) * 4;
  const float4 v = *(const float4*)&src[(long)(k0+lr)*N + n0 + lc];
  ushort4 tv; tv.x=f2bf(v.x); tv.y=f2bf(v.y); tv.z=f2bf(v.z); tv.w=f2bf(v.w);
  *(ushort4*)&tile[lr][lc] = tv;
  __syncthreads();
  ushort4 o;
  o.x = tile[lc+0][lr]; o.y = tile[lc+1][lr];
  o.z = tile[lc+2][lr]; o.w = tile[lc+3][lr];
  *(ushort4*)&dst[(long)(n0+lr)*K + k0 + lc] = o;
}

// kv [b][s][2048] (v in cols 1024..2047, per-head h*64+d) -> vt [(b*16+h)][d][s]
__global__ void vt_k(const u16* __restrict__ kv, u16* __restrict__ dst)
{
  __shared__ u16 tile[32][36];
  const int t = threadIdx.x;
  const int z = blockIdx.z;            // b*16+h
  const int b = z >> 4, h = z & 15;
  const int s0 = blockIdx.x*32, d0 = blockIdx.y*32;
  const int lr = t >> 3, lc = (t & 7) * 4;
  ushort4 v = *(const ushort4*)&kv[(long)(b*2048 + s0+lr)*2048 + 1024 + h*64 + d0 + lc];
  *(ushort4*)&tile[lr][lc] = v;
  __syncthreads();
  ushort4 o;
  o.x = tile[lc+0][lr]; o.y = tile[lc+1][lr];
  o.z = tile[lc+2][lr]; o.w = tile[lc+3][lr];
  *(ushort4*)&dst[(long)z*131072 + (long)(d0+lr)*2048 + s0 + lc] = o;
}

// ---------------------------------------------------------------------------
template<bool WF32>
__global__ void rmsnorm_k(const float* __restrict__ x, const float* __restrict__ w,
                          u16* __restrict__ ob, float* __restrict__ of)
{
  const int row = blockIdx.x, t = threadIdx.x;
  const float4 v = ((const float4*)(x + (long)row*D_))[t];
  float ss = v.x*v.x + v.y*v.y + v.z*v.z + v.w*v.w;
  #pragma unroll
  for (int o=32;o>0;o>>=1) ss += __shfl_down(ss, o);
  __shared__ float red[4];
  if ((t&63)==0) red[t>>6] = ss;
  __syncthreads();
  const float scale = rsqrtf((red[0]+red[1]+red[2]+red[3])*(1.0f/D_) + 1e-6f);
  const float4 wv = ((const float4*)w)[t];
  const float o0=v.x*scale*wv.x, o1=v.y*scale*wv.y, o2=v.z*scale*wv.z, o3=v.w*scale*wv.w;
  const long base = (long)row*D_ + t*4;
  uint2 p; p.x = (u32)f2bf(o0) | ((u32)f2bf(o1)<<16);
  p.y = (u32)f2bf(o2) | ((u32)f2bf(o3)<<16);
  *(uint2*)&ob[base] = p;
  if constexpr (WF32) *(float4*)&of[base] = make_float4(o0,o1,o2,o3);
}

// qf = [q | rope(qr)], kf = [k | rope(kr)]
// qqr: [tok][2048]; kv: [tok][2048]; krt: base hckr+1280, row stride 2304
__global__ void rope_concat_k(const u16* __restrict__ qqr, const u16* __restrict__ kv,
                              const u16* __restrict__ krt,
                              const float* __restrict__ fc, const float* __restrict__ fs,
                              u16* __restrict__ qf, u16* __restrict__ kf)
{
  const int idx = blockIdx.x*256 + threadIdx.x;
  const int j = idx & 31, h = (idx>>5) & 15, bs = idx >> 9;
  if (bs >= NTOK) return;
  const int s = bs & (S_-1);
  const float c = fc[s*32+j], sn = fs[s*32+j];
  const long ib2 = (long)bs*2048 + h*64 + 2*j;
  const long ib1 = (long)bs*2304 + h*64 + 2*j;
  const long ob = (long)bs*2048 + h*128 + 2*j;
  *(u32*)&qf[ob] = *(const u32*)&qqr[ib2];
  *(u32*)&kf[ob] = *(const u32*)&kv[ib2];
  float x0 = bf2f(qqr[ib2+1024]), x1 = bf2f(qqr[ib2+1025]);
  *(u32*)&qf[ob+64] = (u32)f2bf(x0*c - x1*sn) | ((u32)f2bf(x0*sn + x1*c) << 16);
  x0 = bf2f(krt[ib1]); x1 = bf2f(krt[ib1+1]);
  *(u32*)&kf[ob+64] = (u32)f2bf(x0*c - x1*sn) | ((u32)f2bf(x0*sn + x1*c) << 16);
}

// noisy top-2 per token -> eids (i0|i1<<8), gates (g0,g1).  Deterministic.
__global__ void topk_k(const float* __restrict__ h2, const float* __restrict__ wr,
                       const float* __restrict__ br, const float* __restrict__ wn,
                       const float* __restrict__ bn, const float* __restrict__ noise,
                       int* __restrict__ eids, float2* __restrict__ gates)
{
  const int tok = blockIdx.x, t = threadIdx.x;
  const float4 xv = ((const float4*)(h2 + (long)tok*D_))[t];
  const float xs[4] = {xv.x, xv.y, xv.z, xv.w};
  float ar[8], an[8];
  #pragma unroll
  for (int e=0;e<8;e++){ ar[e]=0.f; an[e]=0.f; }
  #pragma unroll
  for (int i=0;i<4;i++){
    const int d = t*4+i;
    const float* wrr = wr + d*8;
    const float* wnr = wn + d*8;
    #pragma unroll
    for (int e=0;e<8;e++){ ar[e] += xs[i]*wrr[e]; an[e] += xs[i]*wnr[e]; }
  }
  #pragma unroll
  for (int e=0;e<8;e++){
    #pragma unroll
    for (int o=32;o>0;o>>=1){ ar[e] += __shfl_down(ar[e], o); an[e] += __shfl_down(an[e], o); }
  }
  __shared__ float rr[4][8], rn[4][8];
  if ((t&63)==0){
    const int w4 = t>>6;
    #pragma unroll
    for (int e=0;e<8;e++){ rr[w4][e]=ar[e]; rn[w4][e]=an[e]; }
  }
  __syncthreads();
  if (t==0){
    float nz[8];
    #pragma unroll
    for (int e=0;e<8;e++){
      const float r  = rr[0][e]+rr[1][e]+rr[2][e]+rr[3][e] + br[e];
      const float ns = rn[0][e]+rn[1][e]+rn[2][e]+rn[3][e] + bn[e];
      const float sp = (ns > 20.f) ? ns : log1pf(expf(ns));
      nz[e] = r + noise[(long)tok*8+e]*sp;
    }
    int i0 = 0;
    #pragma unroll
    for (int e=1;e<8;e++) if (nz[e] > nz[i0]) i0 = e;
    int i1 = -1; float best = -3.0e38f;
    #pragma unroll
    for (int e=0;e<8;e++) if (e != i0 && nz[e] > best){ best = nz[e]; i1 = e; }
    const float e1  = expf(nz[i1]-nz[i0]);
    const float inv = 1.f/(1.f+e1);
    eids[tok] = i0 | (i1 << 8);
    gates[tok] = make_float2(inv, e1*inv);
  }
}

// --- parallel deterministic compact: hist -> scan -> fill --------------------
__global__ void __launch_bounds__(64)
hist_k(const int* __restrict__ eids, int* __restrict__ segcnt)
{
  const int b = blockIdx.x, t = threadIdx.x;
  const int id = eids[b*64 + t];
  const int i0 = id & 255, i1 = (id >> 8) & 255;
  #pragma unroll
  for (int e=0;e<8;e++){
    const u64 m0 = __ballot(i0==e);
    const u64 m1 = __ballot(i1==e);
    if (t==0) segcnt[e*64+b] = __popcll(m0) + __popcll(m1);
  }
}

__global__ void __launch_bounds__(64)
scan_k(const int* __restrict__ segcnt, int* __restrict__ segoff,
       int* __restrict__ cntoff)
{
  const int t = threadIdx.x;
  int base = 0;
  for (int e=0;e<8;e++){
    const int c = segcnt[e*64+t];
    int sc = c;
    #pragma unroll
    for (int o=1;o<64;o<<=1){ int u = __shfl_up(sc, o); if (t >= o) sc += u; }
    const int tot = __shfl(sc, 63);
    segoff[e*64+t] = base + (sc - c);
    if (t==0){ cntoff[e] = tot; cntoff[8+e] = base; }
    base += tot;
  }
}

__global__ void __launch_bounds__(64)
fill_k(const int* __restrict__ eids, const float2* __restrict__ gates,
       const int* __restrict__ segoff, int* __restrict__ idxb,
       float* __restrict__ gvb, int* __restrict__ slotb)
{
  const int b = blockIdx.x, t = threadIdx.x;
  const int tok = b*64 + t;
  const int id = eids[tok];
  const int i0 = id & 255, i1 = (id >> 8) & 255;
  const float2 g = gates[tok];
  const u64 below = ((u64)1 << t) - 1;
  #pragma unroll
  for (int e=0;e<8;e++){
    const u64 m0 = __ballot(i0==e);
    const u64 m1 = __ballot(i1==e);
    if (i0==e){
      const int pos = segoff[e*64+b] + __popcll(m0 & below);
      idxb[pos] = tok; gvb[pos] = g.x; slotb[pos] = 0;
    } else if (i1==e){
      const int pos = segoff[e*64+b] + __popcll(m0) + __popcll(m1 & below);
      idxb[pos] = tok; gvb[pos] = g.y; slotb[pos] = 1;
    }
  }
}

// x1 = x + p0 + p1  (o-proj split-K combine)
__global__ void resid3_k(const float* __restrict__ x, const float* __restrict__ p0,
                         const float* __restrict__ p1, float* __restrict__ o, long n4)
{
  long i = (long)blockIdx.x*blockDim.x + threadIdx.x;
  const long stride = (long)gridDim.x*blockDim.x;
  for (; i<n4; i+=stride){
    const float4 vx = ((const float4*)x)[i];
    const float4 a = ((const float4*)p0)[i];
    const float4 b = ((const float4*)p1)[i];
    ((float4*)o)[i] = make_float4(vx.x+a.x+b.x, vx.y+a.y+b.y,
                                  vx.z+a.z+b.z, vx.w+a.w+b.w);
  }
}

// o = a + b
__global__ void addstore_k(const float* __restrict__ a, const float* __restrict__ b,
                           float* __restrict__ o, long n4)
{
  long i = (long)blockIdx.x*blockDim.x + threadIdx.x;
  const long stride = (long)gridDim.x*blockDim.x;
  for (; i<n4; i+=stride){
    const float4 va = ((const float4*)a)[i];
    const float4 vb = ((const float4*)b)[i];
    ((float4*)o)[i] = make_float4(va.x+vb.x, va.y+vb.y, va.z+vb.z, va.w+vb.w);
  }
}
// o += f0+f1+f2+f3
__global__ void addacc4_k(const float* __restrict__ f0, const float* __restrict__ f1,
                          const float* __restrict__ f2, const float* __restrict__ f3,
                          float* __restrict__ o, long n4)
{
  long i = (long)blockIdx.x*blockDim.x + threadIdx.x;
  const long stride = (long)gridDim.x*blockDim.x;
  for (; i<n4; i+=stride){
    const float4 a = ((const float4*)f0)[i];
    const float4 b = ((const float4*)f1)[i];
    const float4 c = ((const float4*)f2)[i];
    const float4 d = ((const float4*)f3)[i];
    float4 vo = ((const float4*)o)[i];
    ((float4*)o)[i] = make_float4(vo.x+a.x+b.x+c.x+d.x, vo.y+a.y+b.y+c.y+d.y,
                                  vo.z+a.z+b.z+c.z+d.z, vo.w+a.w+b.w+c.w+d.w);
  }
}

// ---------------------------------------------------------------------------
extern "C" void kernel_launch(void* const* d_in, const int* in_sizes, int n_in,
                              void* d_out, int out_size, void* d_ws, size_t ws_size,
                              hipStream_t stream)
{
  const float* x      = (const float*)d_in[0];
  const float* fcos   = (const float*)d_in[1];
  const float* fsin   = (const float*)d_in[2];
  const float* rnoise = (const float*)d_in[3];
  const float* rms1w  = (const float*)d_in[4];
  const float* rms2w  = (const float*)d_in[5];
  const float* w_lq   = (const float*)d_in[6];
  const float* w_lkv  = (const float*)d_in[7];
  const float* w_q    = (const float*)d_in[8];
  const float* w_k    = (const float*)d_in[9];
  const float* w_v    = (const float*)d_in[10];
  const float* w_qr   = (const float*)d_in[11];
  const float* b_qr   = (const float*)d_in[12];
  const float* w_kr   = (const float*)d_in[13];
  const float* b_kr   = (const float*)d_in[14];
  const float* w_o    = (const float*)d_in[15];
  const float* b_o    = (const float*)d_in[16];
  const float* w_route= (const float*)d_in[17];
  const float* b_route= (const float*)d_in[18];
  const float* w_noise= (const float*)d_in[19];
  const float* b_noise= (const float*)d_in[20];
  const float* rW1    = (const float*)d_in[21];
  const float* rb1    = (const float*)d_in[22];
  const float* rW2    = (const float*)d_in[23];
  const float* rb2    = (const float*)d_in[24];
  const float* sW1    = (const float*)d_in[25];
  const float* sb1    = (const float*)d_in[26];
  const float* sW2    = (const float*)d_in[27];
  const float* sb2    = (const float*)d_in[28];

  if (ws_size < 195166208ULL) return;

  char* ws = (char*)d_ws;
  // persistent / phased buffers
  u16*   h_bf    = (u16*)(ws + 0);           // P1
  u16*   hckr    = (u16*)(ws + 8388608);     // P1: [4096][2304] (cq|ckv|kr), 18 MiB
  u16*   qf      = (u16*)(ws + 27262976);    // P1-P2, 16 MiB
  u16*   kf      = (u16*)(ws + 44040192);    // P1-P2, 16 MiB
  u16*   vt      = (u16*)(ws + 60817408);    // P1-P2, 8.25 MiB -> 69468160
  u16*   attn_bf = (u16*)(ws + 69468160);    // P2-P3, 8 MiB
  float* x1      = (float*)(ws + 77856768);  // P3 (dead after addstore)
  float* h2f     = (float*)(ws + 94633984);  // P3 (dead after addstore)
  u16*   h2_bf   = (u16*)(ws + 111411200);   // P3-P4, 8 MiB
  float* fb      = (float*)(ws + 119799808); // P3 o-proj partials / P4 expert partials
  u16*   Wt_g    = (u16*)(ws + 77856768);    // P4: 32 MiB (x1/h2f zone)
  int*   cntoff  = (int*)(ws + 189005824);
  int*   eids    = (int*)(ws + 189006080);
  float2* gatesb = (float2*)(ws + 189022464);
  int*   idxb    = (int*)(ws + 189055232);
  float* gvb     = (float*)(ws + 189088000);
  int*   slotb   = (int*)(ws + 189120768);
  u16*   wo_t    = (u16*)(ws + 189153536);   // 2 MiB (survives to P3)
  int*   segcnt  = (int*)(ws + 191250560);
  int*   segoff  = (int*)(ws + 191252608);
  // temporal overlays (P1)
  u16*   qqr     = (u16*)(ws + 77856768);    // [4096][2048] (q|qr), 16 MiB
  u16*   kv      = (u16*)(ws + 94633984);    // [4096][2048] (k|v), 16 MiB
  u16*   inter   = (u16*)(ws + 0);           // P4 routed: [8192][4096]; shared: [4096][8192]
  // P2 overlays (x1/h2f/h2_bf zone is free during flash)
  float* opart   = (float*)(ws + 77856768);  // [2][4096][1024] f32, 32 MiB
  float2* mlbuf  = (float2*)(ws + 111411200);// [2][32][2048] float2, 1 MiB
  // small weight transposes (P0-P1, overlaid on fb zone)
  u16*   wlqkvkr_t = (u16*)(ws + 119799808); // [2304][1024] (lq|lkv|kr rows)
  u16*   wqqr_t  = (u16*)(ws + 125829120);   // [2048][768]
  u16*   wkv_t   = (u16*)(ws + 128974848);   // [2048][512]

  const dim3 blk(256,1,1);
  #define GEMM(FL, GRID, ...) gemm_k<FL><<<GRID, blk, 0, stream>>>(__VA_ARGS__)
  #define NOSPARSE nullptr,nullptr,nullptr,nullptr,nullptr,nullptr,nullptr,0

  // P0: small weight transposes (f32 [K][N] -> bf16 [N][K])
  tpose_k<<<dim3(24,32),blk,0,stream>>>(w_lq,  wlqkvkr_t,              1024, 768, 0,0);
  tpose_k<<<dim3(16,32),blk,0,stream>>>(w_lkv, wlqkvkr_t + 768*1024,   1024, 512, 0,0);
  tpose_k<<<dim3(32,32),blk,0,stream>>>(w_kr,  wlqkvkr_t + 1280*1024,  1024,1024, 0,0);
  tpose_k<<<dim3(32,24),blk,0,stream>>>(w_q,   wqqr_t,            768,1024, 0,0);
  tpose_k<<<dim3(32,24),blk,0,stream>>>(w_qr,  wqqr_t + 1024*768, 768,1024, 0,0);
  tpose_k<<<dim3(32,16),blk,0,stream>>>(w_k,   wkv_t,             512,1024, 0,0);
  tpose_k<<<dim3(32,16),blk,0,stream>>>(w_v,   wkv_t + 1024*512,  512,1024, 0,0);
  tpose_k<<<dim3(32,32),blk,0,stream>>>(w_o,   wo_t,  1024,1024, 0,0);

  // P1: rmsnorm + projections (merged cq|ckv|kr, q|qr, k|v) + rope
  rmsnorm_k<false><<<NTOK, blk, 0, stream>>>(x, rms1w, h_bf, nullptr);

  GEMM(F_OUTBF16|F_BIASKR, dim3(18,32,1), h_bf,1024,0, wlqkvkr_t,1024,0, hckr,2304,0,
       nullptr, b_kr, nullptr,nullptr,nullptr,nullptr,nullptr,0, 1024, 2304);
  GEMM(F_OUTBF16|F_BIASHI, dim3(16,32,1), hckr,2304,0, wqqr_t,768,0, qqr,2048,0,
       nullptr, b_qr, nullptr,nullptr,nullptr,nullptr,nullptr,0, 768, 2048);
  GEMM(F_OUTBF16, dim3(16,32,1), hckr+768,2304,0, wkv_t,512,0, kv,2048,0, NOSPARSE, 512, 2048);

  rope_concat_k<<<8192, blk, 0, stream>>>(qqr, kv, hckr+1280, fcos, fsin, qf, kf);
  vt_k<<<dim3(64,2,32), blk, 0, stream>>>(kv, vt);

  // P2: flash attention, KV-split x2 (1024 blocks) + merge
  flash_k<<<dim3(32,16,2), blk, 0, stream>>>(qf, kf, vt, opart, mlbuf);
  pvmerge_k<<<NTOK, blk, 0, stream>>>(opart, mlbuf, attn_bf);

  // P3: o-proj (split-K x2 into fb partials, 512 blocks) + combine + rmsnorm2
  GEMM(F_BIAS|F_SPLITK2, dim3(8,32,2), attn_bf,1024,0, wo_t,1024,0, fb,1024,4194304L,
       nullptr, b_o, nullptr,nullptr,nullptr,nullptr,nullptr,0, 512, 1024);
  resid3_k<<<2048, blk, 0, stream>>>(x, fb, fb+4194304L, x1, 1048576L);
  rmsnorm_k<true><<<NTOK, blk, 0, stream>>>(x1, rms2w, h2_bf, h2f);
  topk_k<<<NTOK, blk, 0, stream>>>(h2f, w_route, b_route, w_noise, b_noise, rnoise,
                                   eids, gatesb);
  hist_k<<<64, 64, 0, stream>>>(eids, segcnt);
  scan_k<<<1, 64, 0, stream>>>(segcnt, segoff, cntoff);
  fill_k<<<64, 64, 0, stream>>>(eids, gatesb, segoff, idxb, gvb, slotb);
  addstore_k<<<2048, blk, 0, stream>>>(x1, h2f, (float*)d_out, 1048576L);  // out = x1+h2
  // no fb memset: routed scatter '=' fully covers all 4 fb buffers (r16)

  // P4a: routed experts, 2 groups of 4; G2 split-K x2 into fb[slot*2+kh]
  for (int g=0; g<2; ++g){
    const int eb = g*4;
    tpose_k<<<dim3(128,32,4),blk,0,stream>>>(rW1 + (long)eb*4194304, Wt_g, 1024, 4096,
                                             4194304L, 4194304L);
    GEMM(F_OUTBF16|F_BIAS|F_RELU|F_GATHER|F_EXPB|F_TMFAST, dim3(32,32,4),
         h2_bf,1024,0, Wt_g,1024,4194304L, inter,4096,0,
         nullptr, rb1, nullptr, nullptr, idxb, nullptr, cntoff, eb, 1024, 4096);
    tpose_k<<<dim3(32,128,4),blk,0,stream>>>(rW2 + (long)eb*4194304, Wt_g, 4096, 1024,
                                             4194304L, 4194304L);
    GEMM(F_BIAS|F_SCATTER|F_EXPB|F_SPLITK2|F_TMFAST, dim3(8,32,8),
         inter,4096,0, Wt_g,4096,4194304L, fb,1024,4194304L,
         nullptr, rb2, nullptr, gvb, idxb, slotb, cntoff, eb, 2048, 1024);
  }

  // P4b: shared experts merged (j0|j1): G1 N=8192 single launch (GROUP8); G2 z=4
  tpose_k<<<dim3(128,32,2),blk,0,stream>>>(sW1, Wt_g, 1024, 4096, 4194304L, 4194304L);
  GEMM(F_OUTBF16|F_BIAS|F_RELU|F_GROUP8, dim3(64,32,1), h2_bf,1024,0, Wt_g,1024,0, inter,8192,0,
       nullptr, sb1, nullptr,nullptr,nullptr,nullptr,nullptr,0, 1024, 8192);
  tpose_k<<<dim3(32,128,2),blk,0,stream>>>(sW2, Wt_g, 4096, 1024, 4194304L, 4194304L);
  GEMM(F_BIAS|F_GATEACC|F_EXPB|F_SPLITK2, dim3(8,32,4),
       inter,8192,4096, Wt_g,4096,4194304L, fb,1024,4194304L,
       nullptr, sb2, nullptr,nullptr,nullptr,nullptr,nullptr,0, 2048, 1024);

  // out += fb0+fb1+fb2+fb3
  addacc4_k<<<2048, blk, 0, stream>>>(fb, fb+4194304L, fb+8388608L, fb+12582912L,
                                      (float*)d_out, 1048576L);
}

// Round 24
// 972.093 us; speedup vs baseline: 1.0156x; 1.0156x over previous
//
#include <hip/hip_runtime.h>
#include <cstdint>

typedef unsigned short u16;
typedef unsigned int   u32;
typedef unsigned long long u64;
using short8 = __attribute__((ext_vector_type(8))) short;
using f32x4  = __attribute__((ext_vector_type(4))) float;

#define S_   2048
#define D_   1024
#define NTOK 4096   /* B*S */

__device__ __forceinline__ u16 f2bf(float f){
  u32 u = __float_as_uint(f);
  u32 r = u + 0x7fffu + ((u >> 16) & 1u);   // RNE
  return (u16)(r >> 16);
}
__device__ __forceinline__ float bf2f(u16 h){
  return __uint_as_float(((u32)h) << 16);
}
__device__ __forceinline__ void gld16(const void* g, void* l){
  __builtin_amdgcn_global_load_lds((__attribute__((address_space(1))) void*)(void*)g,
                                   (__attribute__((address_space(3))) void*)l, 16, 0, 0);
}

// ---------------------------------------------------------------------------
// bf16 MFMA GEMM (NT): C[M,N] = A[M,K] * Bt[N,K]^T, 128x128x32 tiles, 4 waves.
// T2 bank-conflict fix (r15, conflicts = 0).  __launch_bounds__(256,4).
// F_TMFAST: tm-fastest decode (sparse XCD balance, r17: -54us).
// F_GROUP8: 8x8 supertile decode (r20 config).
// Final lock-in of the r22 974us configuration (r23 micro-levers regressed).
// ---------------------------------------------------------------------------
enum { F_OUTBF16=1, F_BIAS=2, F_RELU=4, F_RESID=8, F_GATEACC=16,
       F_GATHER=64, F_SCATTER=128, F_EXPB=512, F_SPLITK2=1024, F_BIASHI=2048,
       F_TMFAST=4096, F_BIASKR=8192, F_GROUP8=16384 };

template<int FLAGS>
__global__ void __launch_bounds__(256, 4)
gemm_k(const u16* __restrict__ A, int lda, long sAz,
       const u16* __restrict__ Bt, int ldb, long sBz,
       void* __restrict__ out, int ldo, long sOz,
       float* __restrict__ out2,
       const float* __restrict__ bias,
       const float* __restrict__ resid,
       const float* __restrict__ gv,
       const int* __restrict__ idx,
       const int* __restrict__ slotb,
       const int* __restrict__ cntp, int ebase,
       int K, int ncols)
{
  constexpr int BM = 128, BK = 32;
  const int tid = threadIdx.x;
  const int w = tid >> 6, l = tid & 63;
  const int wr = w >> 1, wc = w & 1;
  const int l4 = l & 15, lh = l >> 4;

  // bijective XCD swizzle
  const int gx = gridDim.x, gy = gridDim.y;
  const int nwg = gx*gy*gridDim.z;
  const int flat = (blockIdx.z*gy + blockIdx.y)*gx + blockIdx.x;
  const int q8 = nwg >> 3, r8 = nwg & 7, xcd = flat & 7, off8 = flat >> 3;
  const int swz = (xcd < r8) ? (xcd*(q8+1) + off8)
                             : (r8*(q8+1) + (xcd-r8)*q8 + off8);
  int tn, tm, z;
  if constexpr (FLAGS & F_TMFAST){
    tm = swz % gy;
    const int rest = swz / gy;
    tn = rest % gx;
    z  = rest / gx;
  } else if constexpr (FLAGS & F_GROUP8){
    const int slice = gx*gy;
    z = swz / slice;
    const int f = swz % slice;
    const int st = f >> 6, within = f & 63;
    const int gx8 = gx >> 3;
    tn = (st % gx8)*8 + (within & 7);
    tm = (st / gx8)*8 + (within >> 3);
  } else {
    tn = swz % gx;
    const int rest = swz / gx;
    tm = rest % gy;
    z  = rest / gy;
  }
  const int ncol0 = tn * 128;

  int kh = 0, ze = z;
  if constexpr (FLAGS & F_SPLITK2){ kh = z & 1; ze = z >> 1; }

  int cnt = 0x7fffffff; long ofs = 0;
  if constexpr (FLAGS & (F_GATHER|F_SCATTER)){
    const int e = ebase + ze;
    cnt = cntp[e]; ofs = (long)cntp[8+e];
    if (tm*BM >= cnt) return;
  }

  const u16 *Abase, *Btbase;
  if constexpr (FLAGS & F_GATHER){
    Abase  = A;                              // rows via idx
    Btbase = Bt + (long)ze*sBz + (long)ncol0*ldb;
  } else if constexpr (FLAGS & F_SCATTER){
    Abase  = A + ofs*lda + (long)tm*BM*lda + (long)kh*K;
    Btbase = Bt + (long)ze*sBz + (long)ncol0*ldb + (long)kh*K;
  } else {
    Abase  = A  + (long)ze*sAz + (long)tm*BM*lda + (long)kh*K;
    Btbase = Bt + (long)ze*sBz + (long)ncol0*ldb + (long)kh*K;
  }

  const int r0 = tid >> 2;
  const int seg = (tid & 3) ^ ((tid >> 3) & 3);   // pre-swizzled source segment
  long aoff0, aoff1;
  if constexpr (FLAGS & F_GATHER){
    const int p0 = tm*BM + r0, p1 = p0 + 64;
    const int t0 = (p0 < cnt) ? idx[ofs + p0] : 0;
    const int t1 = (p1 < cnt) ? idx[ofs + p1] : 0;
    aoff0 = (long)t0*lda; aoff1 = (long)t1*lda;
  } else {
    aoff0 = (long)r0*lda; aoff1 = (long)(r0+64)*lda;
  }
  const u16* pA0 = Abase + aoff0 + seg*8;
  const u16* pA1 = Abase + aoff1 + seg*8;
  const u16* pB0 = Btbase + (long)r0*ldb + seg*8;
  const u16* pB1 = Btbase + (long)(r0+64)*ldb + seg*8;

  __shared__ __align__(16) u16 As[2][BM*BK];
  __shared__ __align__(16) u16 Bs[2][BM*BK];

  f32x4 zero = {0.f,0.f,0.f,0.f};
  f32x4 acc[4][4];
  #pragma unroll
  for (int i=0;i<4;i++)
    #pragma unroll
    for (int j=0;j<4;j++) acc[i][j] = zero;

  const int NK = K >> 5;

  auto stage = [&](int buf, int kt){
    const int k0 = kt*BK;
    gld16(pA0 + k0, &As[buf][(w*64)*8]);
    gld16(pA1 + k0, &As[buf][(256 + w*64)*8]);
    gld16(pB0 + k0, &Bs[buf][(w*64)*8]);
    gld16(pB1 + k0, &Bs[buf][(256 + w*64)*8]);
  };

  stage(0,0);
  __syncthreads();

  const int xr = (l4 >> 1) & 3;                   // read-side involution
  const int lhx = (lh ^ xr) * 8;

  for (int kt=0; kt<NK; ++kt){
    const int cur = kt & 1, nxt = cur ^ 1;
    if (kt+1 < NK) stage(nxt, kt+1);
    short8 a[4], b[4];
    #pragma unroll
    for (int m=0;m<4;m++){
      const int arow = wr*64 + m*16 + l4;
      a[m] = *(const short8*)&As[cur][arow*BK + lhx];
    }
    #pragma unroll
    for (int n=0;n<4;n++){
      const int brow = wc*64 + n*16 + l4;
      b[n] = *(const short8*)&Bs[cur][brow*BK + lhx];
    }
    #pragma unroll
    for (int m=0;m<4;m++)
      #pragma unroll
      for (int n=0;n<4;n++)
        acc[m][n] = __builtin_amdgcn_mfma_f32_16x16x32_bf16(a[m], b[n], acc[m][n], 0, 0, 0);
    __syncthreads();
  }

  // epilogue  (C/D: col = lane&15, row = (lane>>4)*4 + reg)
  float* outf = (float*)out + (long)z*sOz;
  u16*   outh = (u16*)out + (long)z*sOz;
  const float* bp = bias;
  if constexpr (FLAGS & F_EXPB) bp += (long)(ebase+ze)*ncols;
  const long row0 = (long)tm*BM + wr*64;
  #pragma unroll
  for (int m=0;m<4;m++){
    #pragma unroll
    for (int n=0;n<4;n++){
      const int col = ncol0 + wc*64 + n*16 + l4;
      if (col < ncols){
        #pragma unroll
        for (int r=0;r<4;r++){
          const long row = row0 + m*16 + lh*4 + r;
          float v = acc[m][n][r];
          if constexpr (FLAGS & F_BIAS){
            bool addb = true;
            if constexpr (FLAGS & F_SPLITK2) addb = (kh == 0);
            if (addb) v += bp[col];
          }
          if constexpr (FLAGS & F_BIASHI){
            if (col >= 1024) v += bias[col - 1024];
          }
          if constexpr (FLAGS & F_BIASKR){
            if (col >= 1280) v += bias[col - 1280];
          }
          if constexpr (FLAGS & F_RELU) v = fmaxf(v, 0.f);
          if constexpr (FLAGS & F_SCATTER){
            if (row < cnt){
              const long gs = ofs + row;
              const int tok = idx[gs];
              float* dst = (float*)out + (long)(slotb[gs]*2 + kh)*sOz;
              dst[(long)tok*ldo + col] = gv[gs] * v;
            }
          } else if constexpr (FLAGS & F_GATHER){
            if (row < cnt) outh[(ofs + row)*(long)ldo + col] = f2bf(v);
          } else if constexpr (FLAGS & F_GATEACC){
            outf[row*(long)ldo + col] += v;
          } else if constexpr (FLAGS & F_RESID){
            const long off = row*(long)ldo + col;
            outf[off] = resid[off] + v;
          } else if constexpr (FLAGS & F_OUTBF16){
            outh[row*(long)ldo + col] = f2bf(v);
          } else {
            outf[row*(long)ldo + col] = v;
          }
        }
      }
    }
  }
}

// ---------------------------------------------------------------------------
// Flash attention, KV-split x2.  __launch_bounds__(256,2): (256,3) forced
// VGPR 112->84 and spilled (r18: 133->249us); r23 defer-rescale branch pushed
// VGPR 112->124 and regressed.  Proven r14/r22 config, unconditional rescale.
// ---------------------------------------------------------------------------
#define LDP 136

__global__ void __launch_bounds__(256, 2)
flash_k(const u16* __restrict__ qf, const u16* __restrict__ kf,
        const u16* __restrict__ vt, float* __restrict__ opart,
        float2* __restrict__ ml)
{
  const int bh = blockIdx.x;
  const int qt = blockIdx.y;
  const int kvh = blockIdx.z;
  const int b = bh >> 4, h = bh & 15;
  const int tid = threadIdx.x, w = tid >> 6, l = tid & 63;
  const int l4 = l & 15, lh = l >> 4;

  const u16* Qb = qf + (long)b*4194304 + h*128;
  const u16* Kb = kf + (long)b*4194304 + h*128;
  const u16* Vb = vt + (long)bh*131072;

  short8 qa[2][4];
  #pragma unroll
  for (int m=0;m<2;m++)
    #pragma unroll
    for (int ks=0;ks<4;ks++){
      const long row = qt*128 + w*32 + m*16 + l4;
      qa[m][ks] = *(const short8*)(Qb + row*2048 + ks*32 + lh*8);
    }

  __shared__ __align__(16) u16 KPs[128*LDP];
  __shared__ __align__(16) u16 Vs[64*LDP];

  const float SCL = 0.125f * 1.44269504f;
  float mst[2][4], lst[2][4];
  f32x4 o_acc[2][4];
  #pragma unroll
  for (int m=0;m<2;m++)
    #pragma unroll
    for (int r=0;r<4;r++){ mst[m][r] = -3.0e38f; lst[m][r] = 0.f; }
  #pragma unroll
  for (int m=0;m<2;m++)
    #pragma unroll
    for (int n=0;n<4;n++) o_acc[m][n] = (f32x4){0.f,0.f,0.f,0.f};

  const int t0 = kvh*8;
  for (int t=t0; t<t0+8; t++){
    #pragma unroll
    for (int i=0;i<8;i++){
      const int c = i*256 + tid;
      const int kr = c >> 4, kc = (c & 15) * 8;
      const uint4 v = *(const uint4*)(Kb + (long)(t*128+kr)*2048 + kc);
      *(uint4*)&KPs[kr*LDP + kc] = v;
    }
    #pragma unroll
    for (int i=0;i<4;i++){
      const int c = i*256 + tid;
      const int vr = c >> 4, vc = (c & 15) * 8;
      const uint4 v = *(const uint4*)(Vb + (long)vr*2048 + t*128 + vc);
      *(uint4*)&Vs[vr*LDP + vc] = v;
    }
    __syncthreads();

    f32x4 s[2][8];
    #pragma unroll
    for (int m=0;m<2;m++)
      #pragma unroll
      for (int n=0;n<8;n++) s[m][n] = (f32x4){0.f,0.f,0.f,0.f};
    #pragma unroll
    for (int ks=0;ks<4;ks++){
      short8 bn[8];
      #pragma unroll
      for (int n=0;n<8;n++)
        bn[n] = *(const short8*)&KPs[(n*16+l4)*LDP + ks*32 + lh*8];
      #pragma unroll
      for (int m=0;m<2;m++)
        #pragma unroll
        for (int n=0;n<8;n++)
          s[m][n] = __builtin_amdgcn_mfma_f32_16x16x32_bf16(qa[m][ks], bn[n], s[m][n], 0,0,0);
    }
    __syncthreads();

    #pragma unroll
    for (int m=0;m<2;m++){
      #pragma unroll
      for (int r=0;r<4;r++){
        float pm = s[m][0][r];
        #pragma unroll
        for (int n=1;n<8;n++) pm = fmaxf(pm, s[m][n][r]);
        #pragma unroll
        for (int o=1;o<16;o<<=1) pm = fmaxf(pm, __shfl_xor(pm, o));
        const float mnew = fmaxf(mst[m][r], pm);
        const float sf = exp2f((mst[m][r] - mnew)*SCL);
        float rsum = 0.f;
        #pragma unroll
        for (int n=0;n<8;n++){
          const float p = exp2f((s[m][n][r] - mnew)*SCL);
          s[m][n][r] = p;
          rsum += p;
        }
        #pragma unroll
        for (int o=1;o<16;o<<=1) rsum += __shfl_xor(rsum, o);
        lst[m][r] = lst[m][r]*sf + rsum;
        mst[m][r] = mnew;
        #pragma unroll
        for (int n=0;n<4;n++) o_acc[m][n][r] *= sf;
      }
    }
    #pragma unroll
    for (int m=0;m<2;m++)
      #pragma unroll
      for (int n=0;n<8;n++)
        #pragma unroll
        for (int r=0;r<4;r++)
          KPs[(w*32 + m*16 + lh*4 + r)*LDP + n*16 + l4] = f2bf(s[m][n][r]);
    __syncthreads();

    #pragma unroll
    for (int ks=0;ks<4;ks++){
      short8 pa[2], vb[4];
      #pragma unroll
      for (int m=0;m<2;m++)
        pa[m] = *(const short8*)&KPs[(w*32 + m*16 + l4)*LDP + ks*32 + lh*8];
      #pragma unroll
      for (int n=0;n<4;n++)
        vb[n] = *(const short8*)&Vs[(n*16+l4)*LDP + ks*32 + lh*8];
      #pragma unroll
      for (int m=0;m<2;m++)
        #pragma unroll
        for (int n=0;n<4;n++)
          o_acc[m][n] = __builtin_amdgcn_mfma_f32_16x16x32_bf16(pa[m], vb[n], o_acc[m][n], 0,0,0);
    }
    __syncthreads();
  }

  float* Op = opart + (long)kvh*4194304;
  #pragma unroll
  for (int m=0;m<2;m++){
    #pragma unroll
    for (int r=0;r<4;r++){
      const long srow = qt*128 + w*32 + m*16 + lh*4 + r;
      const long obase = ((long)b*2048 + srow)*1024 + h*64;
      #pragma unroll
      for (int n=0;n<4;n++)
        Op[obase + n*16 + l4] = o_acc[m][n][r];
      if (l4 == 0)
        ml[(long)kvh*65536 + (long)bh*2048 + srow] = make_float2(mst[m][r], lst[m][r]);
    }
  }
}

// merge the two KV-half partials -> bf16 attn rows
__global__ void pvmerge_k(const float* __restrict__ opart,
                          const float2* __restrict__ ml,
                          u16* __restrict__ attn)
{
  const int row = blockIdx.x;          // b*2048 + s
  const int t = threadIdx.x;
  const int b = row >> 11, s = row & 2047;
  const int h = t >> 4;
  const float SCL = 0.125f * 1.44269504f;
  const float2 m0 = ml[(long)(b*16+h)*2048 + s];
  const float2 m1 = ml[65536L + (long)(b*16+h)*2048 + s];
  const float mm = fmaxf(m0.x, m1.x);
  const float s0 = exp2f((m0.x - mm)*SCL);
  const float s1 = exp2f((m1.x - mm)*SCL);
  const float inv = 1.f / (m0.y*s0 + m1.y*s1);
  const float4 a = *(const float4*)&opart[(long)row*1024 + t*4];
  const float4 c = *(const float4*)&opart[4194304L + (long)row*1024 + t*4];
  uint2 pk;
  pk.x = (u32)f2bf((a.x*s0 + c.x*s1)*inv) | ((u32)f2bf((a.y*s0 + c.y*s1)*inv) << 16);
  pk.y = (u32)f2bf((a.z*s0 + c.z*s1)*inv) | ((u32)f2bf((a.w*s0 + c.w*s1)*inv) << 16);
  *(uint2*)&attn[(long)row*1024 + t*4] = pk;
}

// ---------------------------------------------------------------------------
// batched transpose f32 [K][N] (ld=N) -> bf16 [N][K] (ld=K); z via strides.
__global__ void tpose_k(const float* __restrict__ src, u16* __restrict__ dst,
                        int K, int N, long szS, long szD)
{
  __shared__ u16 tile[32][36];
  const int t = threadIdx.x;
  src += (long)blockIdx.z*szS; dst += (long)blockIdx.z*szD;
  const int n0 = blockIdx.x*32, k0 = blockIdx.y*32;
  const int lr = t >> 3, lc = (t & 7) * 4;
  const float4 v = *(const float4*)&src[(long)(k0+lr)*N + n0 + lc];
  ushort4 tv; tv.x=f2bf(v.x); tv.y=f2bf(v.y); tv.z=f2bf(v.z); tv.w=f2bf(v.w);
  *(ushort4*)&tile[lr][lc] = tv;
  __syncthreads();
  ushort4 o;
  o.x = tile[lc+0][lr]; o.y = tile[lc+1][lr];
  o.z = tile[lc+2][lr]; o.w = tile[lc+3][lr];
  *(ushort4*)&dst[(long)(n0+lr)*K + k0 + lc] = o;
}

// kv [b][s][2048] (v in cols 1024..2047, per-head h*64+d) -> vt [(b*16+h)][d][s]
__global__ void vt_k(const u16* __restrict__ kv, u16* __restrict__ dst)
{
  __shared__ u16 tile[32][36];
  const int t = threadIdx.x;
  const int z = blockIdx.z;            // b*16+h
  const int b = z >> 4, h = z & 15;
  const int s0 = blockIdx.x*32, d0 = blockIdx.y*32;
  const int lr = t >> 3, lc = (t & 7) * 4;
  ushort4 v = *(const ushort4*)&kv[(long)(b*2048 + s0+lr)*2048 + 1024 + h*64 + d0 + lc];
  *(ushort4*)&tile[lr][lc] = v;
  __syncthreads();
  ushort4 o;
  o.x = tile[lc+0][lr]; o.y = tile[lc+1][lr];
  o.z = tile[lc+2][lr]; o.w = tile[lc+3][lr];
  *(ushort4*)&dst[(long)z*131072 + (long)(d0+lr)*2048 + s0 + lc] = o;
}

// ---------------------------------------------------------------------------
template<bool WF32>
__global__ void rmsnorm_k(const float* __restrict__ x, const float* __restrict__ w,
                          u16* __restrict__ ob, float* __restrict__ of)
{
  const int row = blockIdx.x, t = threadIdx.x;
  const float4 v = ((const float4*)(x + (long)row*D_))[t];
  float ss = v.x*v.x + v.y*v.y + v.z*v.z + v.w*v.w;
  #pragma unroll
  for (int o=32;o>0;o>>=1) ss += __shfl_down(ss, o);
  __shared__ float red[4];
  if ((t&63)==0) red[t>>6] = ss;
  __syncthreads();
  const float scale = rsqrtf((red[0]+red[1]+red[2]+red[3])*(1.0f/D_) + 1e-6f);
  const float4 wv = ((const float4*)w)[t];
  const float o0=v.x*scale*wv.x, o1=v.y*scale*wv.y, o2=v.z*scale*wv.z, o3=v.w*scale*wv.w;
  const long base = (long)row*D_ + t*4;
  uint2 p; p.x = (u32)f2bf(o0) | ((u32)f2bf(o1)<<16);
  p.y = (u32)f2bf(o2) | ((u32)f2bf(o3)<<16);
  *(uint2*)&ob[base] = p;
  if constexpr (WF32) *(float4*)&of[base] = make_float4(o0,o1,o2,o3);
}

// qf = [q | rope(qr)], kf = [k | rope(kr)]
// qqr: [tok][2048]; kv: [tok][2048]; krt: base hckr+1280, row stride 2304
__global__ void rope_concat_k(const u16* __restrict__ qqr, const u16* __restrict__ kv,
                              const u16* __restrict__ krt,
                              const float* __restrict__ fc, const float* __restrict__ fs,
                              u16* __restrict__ qf, u16* __restrict__ kf)
{
  const int idx = blockIdx.x*256 + threadIdx.x;
  const int j = idx & 31, h = (idx>>5) & 15, bs = idx >> 9;
  if (bs >= NTOK) return;
  const int s = bs & (S_-1);
  const float c = fc[s*32+j], sn = fs[s*32+j];
  const long ib2 = (long)bs*2048 + h*64 + 2*j;
  const long ib1 = (long)bs*2304 + h*64 + 2*j;
  const long ob = (long)bs*2048 + h*128 + 2*j;
  *(u32*)&qf[ob] = *(const u32*)&qqr[ib2];
  *(u32*)&kf[ob] = *(const u32*)&kv[ib2];
  float x0 = bf2f(qqr[ib2+1024]), x1 = bf2f(qqr[ib2+1025]);
  *(u32*)&qf[ob+64] = (u32)f2bf(x0*c - x1*sn) | ((u32)f2bf(x0*sn + x1*c) << 16);
  x0 = bf2f(krt[ib1]); x1 = bf2f(krt[ib1+1]);
  *(u32*)&kf[ob+64] = (u32)f2bf(x0*c - x1*sn) | ((u32)f2bf(x0*sn + x1*c) << 16);
}

// noisy top-2 per token -> eids (i0|i1<<8), gates (g0,g1).  Deterministic.
__global__ void topk_k(const float* __restrict__ h2, const float* __restrict__ wr,
                       const float* __restrict__ br, const float* __restrict__ wn,
                       const float* __restrict__ bn, const float* __restrict__ noise,
                       int* __restrict__ eids, float2* __restrict__ gates)
{
  const int tok = blockIdx.x, t = threadIdx.x;
  const float4 xv = ((const float4*)(h2 + (long)tok*D_))[t];
  const float xs[4] = {xv.x, xv.y, xv.z, xv.w};
  float ar[8], an[8];
  #pragma unroll
  for (int e=0;e<8;e++){ ar[e]=0.f; an[e]=0.f; }
  #pragma unroll
  for (int i=0;i<4;i++){
    const int d = t*4+i;
    const float* wrr = wr + d*8;
    const float* wnr = wn + d*8;
    #pragma unroll
    for (int e=0;e<8;e++){ ar[e] += xs[i]*wrr[e]; an[e] += xs[i]*wnr[e]; }
  }
  #pragma unroll
  for (int e=0;e<8;e++){
    #pragma unroll
    for (int o=32;o>0;o>>=1){ ar[e] += __shfl_down(ar[e], o); an[e] += __shfl_down(an[e], o); }
  }
  __shared__ float rr[4][8], rn[4][8];
  if ((t&63)==0){
    const int w4 = t>>6;
    #pragma unroll
    for (int e=0;e<8;e++){ rr[w4][e]=ar[e]; rn[w4][e]=an[e]; }
  }
  __syncthreads();
  if (t==0){
    float nz[8];
    #pragma unroll
    for (int e=0;e<8;e++){
      const float r  = rr[0][e]+rr[1][e]+rr[2][e]+rr[3][e] + br[e];
      const float ns = rn[0][e]+rn[1][e]+rn[2][e]+rn[3][e] + bn[e];
      const float sp = (ns > 20.f) ? ns : log1pf(expf(ns));
      nz[e] = r + noise[(long)tok*8+e]*sp;
    }
    int i0 = 0;
    #pragma unroll
    for (int e=1;e<8;e++) if (nz[e] > nz[i0]) i0 = e;
    int i1 = -1; float best = -3.0e38f;
    #pragma unroll
    for (int e=0;e<8;e++) if (e != i0 && nz[e] > best){ best = nz[e]; i1 = e; }
    const float e1  = expf(nz[i1]-nz[i0]);
    const float inv = 1.f/(1.f+e1);
    eids[tok] = i0 | (i1 << 8);
    gates[tok] = make_float2(inv, e1*inv);
  }
}

// --- parallel deterministic compact: hist -> scan -> fill --------------------
__global__ void __launch_bounds__(64)
hist_k(const int* __restrict__ eids, int* __restrict__ segcnt)
{
  const int b = blockIdx.x, t = threadIdx.x;
  const int id = eids[b*64 + t];
  const int i0 = id & 255, i1 = (id >> 8) & 255;
  #pragma unroll
  for (int e=0;e<8;e++){
    const u64 m0 = __ballot(i0==e);
    const u64 m1 = __ballot(i1==e);
    if (t==0) segcnt[e*64+b] = __popcll(m0) + __popcll(m1);
  }
}

__global__ void __launch_bounds__(64)
scan_k(const int* __restrict__ segcnt, int* __restrict__ segoff,
       int* __restrict__ cntoff)
{
  const int t = threadIdx.x;
  int base = 0;
  for (int e=0;e<8;e++){
    const int c = segcnt[e*64+t];
    int sc = c;
    #pragma unroll
    for (int o=1;o<64;o<<=1){ int u = __shfl_up(sc, o); if (t >= o) sc += u; }
    const int tot = __shfl(sc, 63);
    segoff[e*64+t] = base + (sc - c);
    if (t==0){ cntoff[e] = tot; cntoff[8+e] = base; }
    base += tot;
  }
}

__global__ void __launch_bounds__(64)
fill_k(const int* __restrict__ eids, const float2* __restrict__ gates,
       const int* __restrict__ segoff, int* __restrict__ idxb,
       float* __restrict__ gvb, int* __restrict__ slotb)
{
  const int b = blockIdx.x, t = threadIdx.x;
  const int tok = b*64 + t;
  const int id = eids[tok];
  const int i0 = id & 255, i1 = (id >> 8) & 255;
  const float2 g = gates[tok];
  const u64 below = ((u64)1 << t) - 1;
  #pragma unroll
  for (int e=0;e<8;e++){
    const u64 m0 = __ballot(i0==e);
    const u64 m1 = __ballot(i1==e);
    if (i0==e){
      const int pos = segoff[e*64+b] + __popcll(m0 & below);
      idxb[pos] = tok; gvb[pos] = g.x; slotb[pos] = 0;
    } else if (i1==e){
      const int pos = segoff[e*64+b] + __popcll(m0) + __popcll(m1 & below);
      idxb[pos] = tok; gvb[pos] = g.y; slotb[pos] = 1;
    }
  }
}

// o = a + b
__global__ void addstore_k(const float* __restrict__ a, const float* __restrict__ b,
                           float* __restrict__ o, long n4)
{
  long i = (long)blockIdx.x*blockDim.x + threadIdx.x;
  const long stride = (long)gridDim.x*blockDim.x;
  for (; i<n4; i+=stride){
    const float4 va = ((const float4*)a)[i];
    const float4 vb = ((const float4*)b)[i];
    ((float4*)o)[i] = make_float4(va.x+vb.x, va.y+vb.y, va.z+vb.z, va.w+vb.w);
  }
}
// o += f0+f1+f2+f3
__global__ void addacc4_k(const float* __restrict__ f0, const float* __restrict__ f1,
                          const float* __restrict__ f2, const float* __restrict__ f3,
                          float* __restrict__ o, long n4)
{
  long i = (long)blockIdx.x*blockDim.x + threadIdx.x;
  const long stride = (long)gridDim.x*blockDim.x;
  for (; i<n4; i+=stride){
    const float4 a = ((const float4*)f0)[i];
    const float4 b = ((const float4*)f1)[i];
    const float4 c = ((const float4*)f2)[i];
    const float4 d = ((const float4*)f3)[i];
    float4 vo = ((const float4*)o)[i];
    ((float4*)o)[i] = make_float4(vo.x+a.x+b.x+c.x+d.x, vo.y+a.y+b.y+c.y+d.y,
                                  vo.z+a.z+b.z+c.z+d.z, vo.w+a.w+b.w+c.w+d.w);
  }
}

// ---------------------------------------------------------------------------
extern "C" void kernel_launch(void* const* d_in, const int* in_sizes, int n_in,
                              void* d_out, int out_size, void* d_ws, size_t ws_size,
                              hipStream_t stream)
{
  const float* x      = (const float*)d_in[0];
  const float* fcos   = (const float*)d_in[1];
  const float* fsin   = (const float*)d_in[2];
  const float* rnoise = (const float*)d_in[3];
  const float* rms1w  = (const float*)d_in[4];
  const float* rms2w  = (const float*)d_in[5];
  const float* w_lq   = (const float*)d_in[6];
  const float* w_lkv  = (const float*)d_in[7];
  const float* w_q    = (const float*)d_in[8];
  const float* w_k    = (const float*)d_in[9];
  const float* w_v    = (const float*)d_in[10];
  const float* w_qr   = (const float*)d_in[11];
  const float* b_qr   = (const float*)d_in[12];
  const float* w_kr   = (const float*)d_in[13];
  const float* b_kr   = (const float*)d_in[14];
  const float* w_o    = (const float*)d_in[15];
  const float* b_o    = (const float*)d_in[16];
  const float* w_route= (const float*)d_in[17];
  const float* b_route= (const float*)d_in[18];
  const float* w_noise= (const float*)d_in[19];
  const float* b_noise= (const float*)d_in[20];
  const float* rW1    = (const float*)d_in[21];
  const float* rb1    = (const float*)d_in[22];
  const float* rW2    = (const float*)d_in[23];
  const float* rb2    = (const float*)d_in[24];
  const float* sW1    = (const float*)d_in[25];
  const float* sb1    = (const float*)d_in[26];
  const float* sW2    = (const float*)d_in[27];
  const float* sb2    = (const float*)d_in[28];

  if (ws_size < 195166208ULL) return;

  char* ws = (char*)d_ws;
  // persistent / phased buffers
  u16*   h_bf    = (u16*)(ws + 0);           // P1
  u16*   hckr    = (u16*)(ws + 8388608);     // P1: [4096][2304] (cq|ckv|kr), 18 MiB
  u16*   qf      = (u16*)(ws + 27262976);    // P1-P2, 16 MiB
  u16*   kf      = (u16*)(ws + 44040192);    // P1-P2, 16 MiB
  u16*   vt      = (u16*)(ws + 60817408);    // P1-P2, 8.25 MiB -> 69468160
  u16*   attn_bf = (u16*)(ws + 69468160);    // P2-P3, 8 MiB
  float* x1      = (float*)(ws + 77856768);  // P3 (dead after addstore)
  float* h2f     = (float*)(ws + 94633984);  // P3 (dead after addstore)
  u16*   h2_bf   = (u16*)(ws + 111411200);   // P3-P4, 8 MiB
  float* fb      = (float*)(ws + 119799808); // P4: 4 x 16 MiB partials -> 186908672
  u16*   Wt_g    = (u16*)(ws + 77856768);    // P4: 32 MiB (x1/h2f zone)
  int*   cntoff  = (int*)(ws + 189005824);
  int*   eids    = (int*)(ws + 189006080);
  float2* gatesb = (float2*)(ws + 189022464);
  int*   idxb    = (int*)(ws + 189055232);
  float* gvb     = (float*)(ws + 189088000);
  int*   slotb   = (int*)(ws + 189120768);
  u16*   wo_t    = (u16*)(ws + 189153536);   // 2 MiB (survives to P3)
  int*   segcnt  = (int*)(ws + 191250560);
  int*   segoff  = (int*)(ws + 191252608);
  // temporal overlays (P1)
  u16*   qqr     = (u16*)(ws + 77856768);    // [4096][2048] (q|qr), 16 MiB
  u16*   kv      = (u16*)(ws + 94633984);    // [4096][2048] (k|v), 16 MiB
  u16*   inter   = (u16*)(ws + 0);           // P4 routed: [8192][4096]; shared: [4096][8192]
  // P2 overlays (x1/h2f/h2_bf zone is free during flash)
  float* opart   = (float*)(ws + 77856768);  // [2][4096][1024] f32, 32 MiB
  float2* mlbuf  = (float2*)(ws + 111411200);// [2][32][2048] float2, 1 MiB
  // small weight transposes (P0-P1, overlaid on fb zone)
  u16*   wlqkvkr_t = (u16*)(ws + 119799808); // [2304][1024] (lq|lkv|kr rows)
  u16*   wqqr_t  = (u16*)(ws + 125829120);   // [2048][768]
  u16*   wkv_t   = (u16*)(ws + 128974848);   // [2048][512]

  const dim3 blk(256,1,1);
  #define GEMM(FL, GRID, ...) gemm_k<FL><<<GRID, blk, 0, stream>>>(__VA_ARGS__)
  #define NOSPARSE nullptr,nullptr,nullptr,nullptr,nullptr,nullptr,nullptr,0

  // P0: small weight transposes (f32 [K][N] -> bf16 [N][K])
  tpose_k<<<dim3(24,32),blk,0,stream>>>(w_lq,  wlqkvkr_t,              1024, 768, 0,0);
  tpose_k<<<dim3(16,32),blk,0,stream>>>(w_lkv, wlqkvkr_t + 768*1024,   1024, 512, 0,0);
  tpose_k<<<dim3(32,32),blk,0,stream>>>(w_kr,  wlqkvkr_t + 1280*1024,  1024,1024, 0,0);
  tpose_k<<<dim3(32,24),blk,0,stream>>>(w_q,   wqqr_t,            768,1024, 0,0);
  tpose_k<<<dim3(32,24),blk,0,stream>>>(w_qr,  wqqr_t + 1024*768, 768,1024, 0,0);
  tpose_k<<<dim3(32,16),blk,0,stream>>>(w_k,   wkv_t,             512,1024, 0,0);
  tpose_k<<<dim3(32,16),blk,0,stream>>>(w_v,   wkv_t + 1024*512,  512,1024, 0,0);
  tpose_k<<<dim3(32,32),blk,0,stream>>>(w_o,   wo_t,  1024,1024, 0,0);

  // P1: rmsnorm + projections (merged cq|ckv|kr, q|qr, k|v) + rope
  rmsnorm_k<false><<<NTOK, blk, 0, stream>>>(x, rms1w, h_bf, nullptr);

  GEMM(F_OUTBF16|F_BIASKR, dim3(18,32,1), h_bf,1024,0, wlqkvkr_t,1024,0, hckr,2304,0,
       nullptr, b_kr, nullptr,nullptr,nullptr,nullptr,nullptr,0, 1024, 2304);
  GEMM(F_OUTBF16|F_BIASHI, dim3(16,32,1), hckr,2304,0, wqqr_t,768,0, qqr,2048,0,
       nullptr, b_qr, nullptr,nullptr,nullptr,nullptr,nullptr,0, 768, 2048);
  GEMM(F_OUTBF16, dim3(16,32,1), hckr+768,2304,0, wkv_t,512,0, kv,2048,0, NOSPARSE, 512, 2048);

  rope_concat_k<<<8192, blk, 0, stream>>>(qqr, kv, hckr+1280, fcos, fsin, qf, kf);
  vt_k<<<dim3(64,2,32), blk, 0, stream>>>(kv, vt);

  // P2: flash attention, KV-split x2 (1024 blocks) + merge
  flash_k<<<dim3(32,16,2), blk, 0, stream>>>(qf, kf, vt, opart, mlbuf);
  pvmerge_k<<<NTOK, blk, 0, stream>>>(opart, mlbuf, attn_bf);

  // P3: o-proj + rmsnorm2 + router
  GEMM(F_BIAS|F_RESID, dim3(8,32,1), attn_bf,1024,0, wo_t,1024,0, x1,1024,0,
       nullptr, b_o, x, nullptr,nullptr,nullptr,nullptr,0, 1024, 1024);
  rmsnorm_k<true><<<NTOK, blk, 0, stream>>>(x1, rms2w, h2_bf, h2f);
  topk_k<<<NTOK, blk, 0, stream>>>(h2f, w_route, b_route, w_noise, b_noise, rnoise,
                                   eids, gatesb);
  hist_k<<<64, 64, 0, stream>>>(eids, segcnt);
  scan_k<<<1, 64, 0, stream>>>(segcnt, segoff, cntoff);
  fill_k<<<64, 64, 0, stream>>>(eids, gatesb, segoff, idxb, gvb, slotb);
  addstore_k<<<2048, blk, 0, stream>>>(x1, h2f, (float*)d_out, 1048576L);  // out = x1+h2
  // no fb memset: routed scatter '=' fully covers all 4 fb buffers (r16)

  // P4a: routed experts, 2 groups of 4; G2 split-K x2 into fb[slot*2+kh]
  for (int g=0; g<2; ++g){
    const int eb = g*4;
    tpose_k<<<dim3(128,32,4),blk,0,stream>>>(rW1 + (long)eb*4194304, Wt_g, 1024, 4096,
                                             4194304L, 4194304L);
    GEMM(F_OUTBF16|F_BIAS|F_RELU|F_GATHER|F_EXPB|F_TMFAST, dim3(32,32,4),
         h2_bf,1024,0, Wt_g,1024,4194304L, inter,4096,0,
         nullptr, rb1, nullptr, nullptr, idxb, nullptr, cntoff, eb, 1024, 4096);
    tpose_k<<<dim3(32,128,4),blk,0,stream>>>(rW2 + (long)eb*4194304, Wt_g, 4096, 1024,
                                             4194304L, 4194304L);
    GEMM(F_BIAS|F_SCATTER|F_EXPB|F_SPLITK2|F_TMFAST, dim3(8,32,8),
         inter,4096,0, Wt_g,4096,4194304L, fb,1024,4194304L,
         nullptr, rb2, nullptr, gvb, idxb, slotb, cntoff, eb, 2048, 1024);
  }

  // P4b: shared experts merged (j0|j1): G1 N=8192 single launch (GROUP8); G2 z=4
  tpose_k<<<dim3(128,32,2),blk,0,stream>>>(sW1, Wt_g, 1024, 4096, 4194304L, 4194304L);
  GEMM(F_OUTBF16|F_BIAS|F_RELU|F_GROUP8, dim3(64,32,1), h2_bf,1024,0, Wt_g,1024,0, inter,8192,0,
       nullptr, sb1, nullptr,nullptr,nullptr,nullptr,nullptr,0, 1024, 8192);
  tpose_k<<<dim3(32,128,2),blk,0,stream>>>(sW2, Wt_g, 4096, 1024, 4194304L, 4194304L);
  GEMM(F_BIAS|F_GATEACC|F_EXPB|F_SPLITK2, dim3(8,32,4),
       inter,8192,4096, Wt_g,4096,4194304L, fb,1024,4194304L,
       nullptr, sb2, nullptr,nullptr,nullptr,nullptr,nullptr,0, 2048, 1024);

  // out += fb0+fb1+fb2+fb3
  addacc4_k<<<2048, blk, 0, stream>>>(fb, fb+4194304L, fb+8388608L, fb+12582912L,
                                      (float*)d_out, 1048576L);
}